// Round 6
// baseline (478.000 us; speedup 1.0000x reference)
//
#include <hip/hip_runtime.h>
#include <cstdint>
#include <cstddef>

#define N_NODES 50000
#define N_EDGES 800000
#define ET (N_EDGES + N_NODES)   // edges + self loops
#define D 128
#define NLAYERS 3
#define SLOPE 0.2f
#define NB_SCAN ((N_NODES + 1023) / 1024)   // 49 blocks

typedef __bf16 bf16x8 __attribute__((ext_vector_type(8)));
typedef float  f32x4  __attribute__((ext_vector_type(4)));
typedef float  f32x2  __attribute__((ext_vector_type(2)));

// ---- bf16 split helpers (round-to-nearest-even) ----
__device__ __forceinline__ unsigned short f2bf_rne(float v) {
    unsigned u = __float_as_uint(v);
    u += 0x7fffu + ((u >> 16) & 1u);
    return (unsigned short)(u >> 16);
}
__device__ __forceinline__ float bf2f(unsigned short h) {
    return __uint_as_float(((unsigned)h) << 16);
}
// unpack packed pair of bf16 (lo in bits 0-15, hi in 16-31) -> f32x2
__device__ __forceinline__ f32x2 unpack_bf2(unsigned u) {
    f32x2 r;
    r.x = __uint_as_float(u << 16);
    r.y = __uint_as_float(u & 0xffff0000u);
    return r;
}

// ================= prep: split fp32 -> bf16 hi/lo ==================
__global__ void split_x_kernel(const float* __restrict__ x,
                               unsigned short* __restrict__ hhi,
                               unsigned short* __restrict__ hlo)
{
    int i = blockIdx.x * blockDim.x + threadIdx.x;   // float4 index
    if (i >= (N_NODES * D) / 4) return;
    float4 v = ((const float4*)x)[i];
    unsigned short h0 = f2bf_rne(v.x), h1 = f2bf_rne(v.y);
    unsigned short h2 = f2bf_rne(v.z), h3 = f2bf_rne(v.w);
    unsigned short l0 = f2bf_rne(v.x - bf2f(h0)), l1 = f2bf_rne(v.y - bf2f(h1));
    unsigned short l2 = f2bf_rne(v.z - bf2f(h2)), l3 = f2bf_rne(v.w - bf2f(h3));
    uint2 hw, lw;
    hw.x = (unsigned)h0 | ((unsigned)h1 << 16);
    hw.y = (unsigned)h2 | ((unsigned)h3 << 16);
    lw.x = (unsigned)l0 | ((unsigned)l1 << 16);
    lw.y = (unsigned)l2 | ((unsigned)l3 << 16);
    ((uint2*)hhi)[i] = hw;
    ((uint2*)hlo)[i] = lw;
}

// transpose + split weights: W[l][k][n] -> Wt[l][n][k] hi/lo for both mats
__global__ void prep_weights_kernel(const float* __restrict__ Wl,
                                    const float* __restrict__ Wr,
                                    unsigned short* __restrict__ wlh, unsigned short* __restrict__ wll,
                                    unsigned short* __restrict__ wrh, unsigned short* __restrict__ wrl)
{
    int idx = blockIdx.x * blockDim.x + threadIdx.x;
    if (idx >= NLAYERS * D * D) return;
    int l   = idx / (D * D);
    int rem = idx - l * D * D;
    int kk  = rem / D;
    int nn  = rem - kk * D;
    int tp  = l * D * D + nn * D + kk;
    float v = Wl[idx];
    unsigned short h = f2bf_rne(v);
    wlh[tp] = h;
    wll[tp] = f2bf_rne(v - bf2f(h));
    v = Wr[idx];
    h = f2bf_rne(v);
    wrh[tp] = h;
    wrl[tp] = f2bf_rne(v - bf2f(h));
}

// ================= CSR build ==================
__global__ void degree_kernel(const int* __restrict__ dstp, int* __restrict__ deg)
{
    int e = blockIdx.x * blockDim.x + threadIdx.x;
    if (e >= ET) return;
    int dt = (e < N_EDGES) ? dstp[e] : e - N_EDGES;
    atomicAdd(deg + dt, 1);
}

// hierarchical scan: per-block inclusive scan + block sums
__global__ void scan1_kernel(const int* __restrict__ deg,
                             int* __restrict__ incl, int* __restrict__ bsum)
{
    __shared__ int tmp[1024];
    int tid = threadIdx.x;
    int i = blockIdx.x * 1024 + tid;
    int v = (i < N_NODES) ? deg[i] : 0;
    tmp[tid] = v;
    __syncthreads();
    #pragma unroll
    for (int o = 1; o < 1024; o <<= 1) {
        int t = (tid >= o) ? tmp[tid - o] : 0;
        __syncthreads();
        tmp[tid] += t;
        __syncthreads();
    }
    if (i < N_NODES) incl[i] = tmp[tid];
    if (tid == 1023) bsum[blockIdx.x] = tmp[1023];
}

// one wave: exclusive scan of the NB_SCAN block sums (+ total at bsum[NB_SCAN])
__global__ void scan2_kernel(int* __restrict__ bsum)
{
    int lane = threadIdx.x;
    int v = (lane < NB_SCAN) ? bsum[lane] : 0;
    int orig = v;
    #pragma unroll
    for (int o = 1; o < 64; o <<= 1) {
        int t = __shfl_up(v, o, 64);
        if (lane >= o) v += t;
    }
    if (lane < NB_SCAN) bsum[lane] = v - orig;    // exclusive
    if (lane == 63)     bsum[NB_SCAN] = v;        // grand total
}

// finalize: off[] (exclusive global) and cursor[] copy
__global__ void scan3_kernel(const int* __restrict__ deg, const int* __restrict__ incl,
                             const int* __restrict__ bsum,
                             int* __restrict__ off, int* __restrict__ cursor)
{
    int i = blockIdx.x * blockDim.x + threadIdx.x;
    if (i < N_NODES) {
        int e = incl[i] - deg[i] + bsum[i >> 10];
        off[i] = e;
        cursor[i] = e;
    } else if (i == N_NODES) {
        off[N_NODES] = bsum[NB_SCAN];
    }
}

__global__ void scatter_kernel(const int* __restrict__ srcp, const int* __restrict__ dstp,
                               int* __restrict__ cursor, int* __restrict__ esrc)
{
    int e = blockIdx.x * blockDim.x + threadIdx.x;
    if (e >= ET) return;
    int s, dt;
    if (e < N_EDGES) { s = srcp[e]; dt = dstp[e]; }
    else             { s = e - N_EDGES; dt = s; }
    int pos = atomicAdd(cursor + dt, 1);
    esrc[pos] = s;
}

// ============ MFMA dual GEMM, 3-term bf16x2, register-blocked + B double-buffer ======
// Wave tile: 32 rows x 64 cols. Block = 4 waves = 128 rows; grid = rowBlocks x 2 colHalves.
#define LOADB(BLH, BLL, BRH, BRL, n0)                                     \
    {   size_t boff = (size_t)((n0) + gl) * D + kg * 8;                   \
        _Pragma("unroll")                                                 \
        for (int ks = 0; ks < 4; ks++) {                                  \
            BLH[ks] = *(const bf16x8*)(wlh + boff + ks * 32);             \
            BLL[ks] = *(const bf16x8*)(wll + boff + ks * 32);             \
            BRH[ks] = *(const bf16x8*)(wrh + boff + ks * 32);             \
            BRL[ks] = *(const bf16x8*)(wrl + boff + ks * 32);             \
        } }

#define COMPUTE(BLH, BLL, BRH, BRL, n0)                                              \
    {   f32x4 accl0 = {0.f,0.f,0.f,0.f}, accr0 = {0.f,0.f,0.f,0.f};                  \
        f32x4 accl1 = {0.f,0.f,0.f,0.f}, accr1 = {0.f,0.f,0.f,0.f};                  \
        _Pragma("unroll")                                                            \
        for (int ks = 0; ks < 4; ks++) {                                             \
            accl0 = __builtin_amdgcn_mfma_f32_16x16x32_bf16(Ah0[ks], BLH[ks], accl0, 0, 0, 0); \
            accl0 = __builtin_amdgcn_mfma_f32_16x16x32_bf16(Al0[ks], BLH[ks], accl0, 0, 0, 0); \
            accl0 = __builtin_amdgcn_mfma_f32_16x16x32_bf16(Ah0[ks], BLL[ks], accl0, 0, 0, 0); \
            accr0 = __builtin_amdgcn_mfma_f32_16x16x32_bf16(Ah0[ks], BRH[ks], accr0, 0, 0, 0); \
            accr0 = __builtin_amdgcn_mfma_f32_16x16x32_bf16(Al0[ks], BRH[ks], accr0, 0, 0, 0); \
            accr0 = __builtin_amdgcn_mfma_f32_16x16x32_bf16(Ah0[ks], BRL[ks], accr0, 0, 0, 0); \
            accl1 = __builtin_amdgcn_mfma_f32_16x16x32_bf16(Ah1[ks], BLH[ks], accl1, 0, 0, 0); \
            accl1 = __builtin_amdgcn_mfma_f32_16x16x32_bf16(Al1[ks], BLH[ks], accl1, 0, 0, 0); \
            accl1 = __builtin_amdgcn_mfma_f32_16x16x32_bf16(Ah1[ks], BLL[ks], accl1, 0, 0, 0); \
            accr1 = __builtin_amdgcn_mfma_f32_16x16x32_bf16(Ah1[ks], BRH[ks], accr1, 0, 0, 0); \
            accr1 = __builtin_amdgcn_mfma_f32_16x16x32_bf16(Al1[ks], BRH[ks], accr1, 0, 0, 0); \
            accr1 = __builtin_amdgcn_mfma_f32_16x16x32_bf16(Ah1[ks], BRL[ks], accr1, 0, 0, 0); \
        }                                                                            \
        float blc = bl[(n0) + gl], brc = br[(n0) + gl];                              \
        _Pragma("unroll")                                                            \
        for (int r = 0; r < 4; r++) {                                                \
            int row0 = m0 + kg * 4 + r;                                              \
            if (row0 < n) {                                                          \
                xlb[(size_t)row0 * D + (n0) + gl] = f2bf_rne(accl0[r] + blc);        \
                xr [(size_t)row0 * D + (n0) + gl] = accr0[r] + brc;                  \
            }                                                                        \
            int row1 = m0 + 16 + kg * 4 + r;                                         \
            if (row1 < n) {                                                          \
                xlb[(size_t)row1 * D + (n0) + gl] = f2bf_rne(accl1[r] + blc);        \
                xr [(size_t)row1 * D + (n0) + gl] = accr1[r] + brc;                  \
            }                                                                        \
        } }

__global__ __launch_bounds__(256, 2)
void gemm_mfma_kernel(const unsigned short* __restrict__ hhi,
                      const unsigned short* __restrict__ hlo,
                      const unsigned short* __restrict__ wlh,
                      const unsigned short* __restrict__ wll,
                      const unsigned short* __restrict__ wrh,
                      const unsigned short* __restrict__ wrl,
                      const float* __restrict__ bl, const float* __restrict__ br,
                      unsigned short* __restrict__ xlb, float* __restrict__ xr, int n)
{
    int lane = threadIdx.x & 63;
    int wid  = threadIdx.x >> 6;          // 0..3
    int rowB = blockIdx.x >> 1;
    int c0   = (blockIdx.x & 1) * 64;     // column half
    int m0   = (rowB * 4 + wid) * 32;     // this wave's 32 rows
    if (m0 >= n) return;
    int gl = lane & 15;
    int kg = lane >> 4;

    // A fragments: 2 row-tiles x 4 ks x hi/lo, held in registers for the whole kernel
    int ar0 = m0 + gl;      if (ar0 >= n) ar0 = n - 1;
    int ar1 = m0 + 16 + gl; if (ar1 >= n) ar1 = n - 1;
    const unsigned short* ah0 = hhi + (size_t)ar0 * D + kg * 8;
    const unsigned short* al0 = hlo + (size_t)ar0 * D + kg * 8;
    const unsigned short* ah1 = hhi + (size_t)ar1 * D + kg * 8;
    const unsigned short* al1 = hlo + (size_t)ar1 * D + kg * 8;
    bf16x8 Ah0[4], Al0[4], Ah1[4], Al1[4];
    #pragma unroll
    for (int ks = 0; ks < 4; ks++) {
        Ah0[ks] = *(const bf16x8*)(ah0 + ks * 32);
        Al0[ks] = *(const bf16x8*)(al0 + ks * 32);
        Ah1[ks] = *(const bf16x8*)(ah1 + ks * 32);
        Al1[ks] = *(const bf16x8*)(al1 + ks * 32);
    }

    // B ping-pong buffers: compute nt with one while prefetching nt+1 into the other
    bf16x8 B0lh[4], B0ll[4], B0rh[4], B0rl[4];
    bf16x8 B1lh[4], B1ll[4], B1rh[4], B1rl[4];

    LOADB(B0lh, B0ll, B0rh, B0rl, c0);
    LOADB(B1lh, B1ll, B1rh, B1rl, c0 + 16);
    COMPUTE(B0lh, B0ll, B0rh, B0rl, c0);
    LOADB(B0lh, B0ll, B0rh, B0rl, c0 + 32);
    COMPUTE(B1lh, B1ll, B1rh, B1rl, c0 + 16);
    LOADB(B1lh, B1ll, B1rh, B1rl, c0 + 48);
    COMPUTE(B0lh, B0ll, B0rh, B0rl, c0 + 32);
    COMPUTE(B1lh, B1ll, B1rh, B1rl, c0 + 48);
}

// ============ fused per-node GATv2: 8 edges/wave, 8 lanes/edge, packed f32x2 =========
// defer-max online softmax (THR=8): common path has no acc rescale.
// LAST=1: fuse log_softmax, write fp32 out. LAST=0: write h as bf16 hi/lo.
template <int LAST>
__global__ void node_attn_kernel(const unsigned short* __restrict__ xlb,
                                 const float* __restrict__ xr,
                                 const float* __restrict__ att,
                                 const float* __restrict__ bias,
                                 const int* __restrict__ off,
                                 const int* __restrict__ esrc,
                                 float* __restrict__ outF,
                                 unsigned short* __restrict__ hhi,
                                 unsigned short* __restrict__ hlo)
{
    int i    = (int)((blockIdx.x * (size_t)blockDim.x + threadIdx.x) >> 6);
    int lane = threadIdx.x & 63;
    if (i >= N_NODES) return;
    int g  = lane >> 3;     // edge slot 0..7
    int gl = lane & 7;      // lane within group
    int fb = gl * 16;       // this lane's 16 features

    f32x2 aa[8], rr[8];
    {
        const uint4* ap = (const uint4*)(att + fb);
        const uint4* rp = (const uint4*)(xr + (size_t)i * D + fb);
        #pragma unroll
        for (int q = 0; q < 4; q++) {
            uint4 a4 = ap[q], r4 = rp[q];
            aa[q*2+0].x = __uint_as_float(a4.x); aa[q*2+0].y = __uint_as_float(a4.y);
            aa[q*2+1].x = __uint_as_float(a4.z); aa[q*2+1].y = __uint_as_float(a4.w);
            rr[q*2+0].x = __uint_as_float(r4.x); rr[q*2+0].y = __uint_as_float(r4.y);
            rr[q*2+1].x = __uint_as_float(r4.z); rr[q*2+1].y = __uint_as_float(r4.w);
        }
    }

    float m = -1e30f, l = 0.f;
    f32x2 acc[8];
    #pragma unroll
    for (int j = 0; j < 8; j++) acc[j] = (f32x2){0.f, 0.f};

    int k    = off[i];
    int kEnd = off[i + 1];

    int kk = k + g;
    bool valid = kk < kEnd;
    int s0 = esrc[valid ? kk : kEnd - 1];
    const unsigned short* xp0 = xlb + (size_t)s0 * D + fb;
    uint4 x4a = *(const uint4*)(xp0);
    uint4 x4b = *(const uint4*)(xp0 + 8);

    while (k < kEnd) {
        int kn = k + 8;
        uint4 nx4a = x4a, nx4b = x4b;
        bool nvalid = false;
        if (kn < kEnd) {                       // wave-uniform: prefetch next 8 edges
            int nkk = kn + g;
            nvalid = nkk < kEnd;
            int ns = esrc[nvalid ? nkk : kEnd - 1];
            const unsigned short* nxp = xlb + (size_t)ns * D + fb;
            nx4a = *(const uint4*)(nxp);
            nx4b = *(const uint4*)(nxp + 8);
        }
        // unpack 16 bf16 -> 8 f32x2
        f32x2 xx[8];
        xx[0] = unpack_bf2(x4a.x); xx[1] = unpack_bf2(x4a.y);
        xx[2] = unpack_bf2(x4a.z); xx[3] = unpack_bf2(x4a.w);
        xx[4] = unpack_bf2(x4b.x); xx[5] = unpack_bf2(x4b.y);
        xx[6] = unpack_bf2(x4b.z); xx[7] = unpack_bf2(x4b.w);
        // packed score partial: att . leaky_relu(x + r)
        f32x2 sc2 = {0.f, 0.f};
        #pragma unroll
        for (int j = 0; j < 8; j++) {
            f32x2 v  = xx[j] + rr[j];
            f32x2 lv = __builtin_elementwise_max(v, v * SLOPE);
            sc2 = sc2 + lv * aa[j];
        }
        float sc = sc2.x + sc2.y;
        sc += __shfl_xor(sc, 1, 64);
        sc += __shfl_xor(sc, 2, 64);
        sc += __shfl_xor(sc, 4, 64);
        // defer-max online softmax
        if (__any(sc > m + 8.f)) {
            // rare path: rescale (groups with no growth get f=1, harmless)
            float mn = fmaxf(m, sc);
            float f  = __expf(m - mn);
            float p  = valid ? __expf(sc - mn) : 0.f;
            l = l * f + p;
            f32x2 f2 = {f, f}, p2 = {p, p};
            #pragma unroll
            for (int j = 0; j < 8; j++) acc[j] = acc[j] * f2 + xx[j] * p2;
            m = mn;
        } else {
            // common path: no rescale
            float p = valid ? __expf(sc - m) : 0.f;
            l += p;
            f32x2 p2 = {p, p};
            #pragma unroll
            for (int j = 0; j < 8; j++) acc[j] = acc[j] + xx[j] * p2;
        }
        x4a = nx4a; x4b = nx4b; valid = nvalid;
        k = kn;
    }

    // merge the 8 groups' online-softmax states (xor 8, 16, 32)
    #pragma unroll
    for (int o = 8; o <= 32; o <<= 1) {
        float mo  = __shfl_xor(m, o, 64);
        float lo2 = __shfl_xor(l, o, 64);
        float mn  = fmaxf(m, mo);
        float f1  = __expf(m - mn);
        float f2s = __expf(mo - mn);
        l = l * f1 + lo2 * f2s;
        f32x2 f1v = {f1, f1}, f2v = {f2s, f2s};
        #pragma unroll
        for (int j = 0; j < 8; j++) {
            f32x2 ao;
            ao.x = __shfl_xor(acc[j].x, o, 64);
            ao.y = __shfl_xor(acc[j].y, o, 64);
            acc[j] = acc[j] * f1v + ao * f2v;
        }
        m = mn;
    }

    float inv = 1.f / (l + 1e-16f);
    f32x2 hv[8];
    {
        const uint4* bp = (const uint4*)(bias + fb);
        #pragma unroll
        for (int q = 0; q < 4; q++) {
            uint4 b4 = bp[q];
            f32x2 b0; b0.x = __uint_as_float(b4.x); b0.y = __uint_as_float(b4.y);
            f32x2 b1; b1.x = __uint_as_float(b4.z); b1.y = __uint_as_float(b4.w);
            f32x2 iv = {inv, inv};
            f32x2 z  = {0.f, 0.f};
            hv[q*2+0] = __builtin_elementwise_max(acc[q*2+0] * iv + b0, z);
            hv[q*2+1] = __builtin_elementwise_max(acc[q*2+1] * iv + b1, z);
        }
    }

    if (LAST) {
        float mx = fmaxf(hv[0].x, hv[0].y);
        #pragma unroll
        for (int j = 1; j < 8; j++) mx = fmaxf(mx, fmaxf(hv[j].x, hv[j].y));
        mx = fmaxf(mx, __shfl_xor(mx, 1, 64));
        mx = fmaxf(mx, __shfl_xor(mx, 2, 64));
        mx = fmaxf(mx, __shfl_xor(mx, 4, 64));
        float se = 0.f;
        #pragma unroll
        for (int j = 0; j < 8; j++) se += __expf(hv[j].x - mx) + __expf(hv[j].y - mx);
        se += __shfl_xor(se, 1, 64);
        se += __shfl_xor(se, 2, 64);
        se += __shfl_xor(se, 4, 64);
        float ls = logf(se) + mx;
        if (g == 0) {
            float* dst = outF + (size_t)i * D + fb;
            #pragma unroll
            for (int q = 0; q < 4; q++) {
                float4 o4 = make_float4(hv[q*2].x - ls, hv[q*2].y - ls,
                                        hv[q*2+1].x - ls, hv[q*2+1].y - ls);
                *(float4*)(dst + q * 4) = o4;
            }
        }
    } else {
        if (g < 2) {
            unsigned pk[8];
            #pragma unroll
            for (int j = 0; j < 8; j++) {
                float v0 = hv[j].x, v1 = hv[j].y;
                unsigned short h0 = f2bf_rne(v0), h1 = f2bf_rne(v1);
                if (g == 0) pk[j] = (unsigned)h0 | ((unsigned)h1 << 16);
                else {
                    unsigned short l0 = f2bf_rne(v0 - bf2f(h0));
                    unsigned short l1 = f2bf_rne(v1 - bf2f(h1));
                    pk[j] = (unsigned)l0 | ((unsigned)l1 << 16);
                }
            }
            unsigned short* dst = (g == 0 ? hhi : hlo) + (size_t)i * D + fb;
            uint4 w0 = make_uint4(pk[0], pk[1], pk[2], pk[3]);
            uint4 w1 = make_uint4(pk[4], pk[5], pk[6], pk[7]);
            *(uint4*)(dst)     = w0;
            *(uint4*)(dst + 8) = w1;
        }
    }
}

extern "C" void kernel_launch(void* const* d_in, const int* in_sizes, int n_in,
                              void* d_out, int out_size, void* d_ws, size_t ws_size,
                              hipStream_t stream)
{
    const float* x    = (const float*)d_in[0];
    const int*   ei   = (const int*)  d_in[1];
    const float* Wl   = (const float*)d_in[2];
    const float* bl   = (const float*)d_in[3];
    const float* Wr   = (const float*)d_in[4];
    const float* br   = (const float*)d_in[5];
    const float* att  = (const float*)d_in[6];
    const float* bias = (const float*)d_in[7];
    float* out = (float*)d_out;

    const int* srcp = ei;
    const int* dstp = ei + N_EDGES;

    const size_t ND = (size_t)N_NODES * D;
    const size_t WSZ = (size_t)NLAYERS * D * D;
    char* ws = (char*)d_ws;
    unsigned short* xlb = (unsigned short*)ws; ws += ND * sizeof(unsigned short);
    float* xr  = (float*)ws;                   ws += ND * sizeof(float);
    unsigned short* hhi = (unsigned short*)ws; ws += ND * sizeof(unsigned short);
    unsigned short* hlo = (unsigned short*)ws; ws += ND * sizeof(unsigned short);
    unsigned short* wlh = (unsigned short*)ws; ws += WSZ * sizeof(unsigned short);
    unsigned short* wll = (unsigned short*)ws; ws += WSZ * sizeof(unsigned short);
    unsigned short* wrh = (unsigned short*)ws; ws += WSZ * sizeof(unsigned short);
    unsigned short* wrl = (unsigned short*)ws; ws += WSZ * sizeof(unsigned short);
    int* deg    = (int*)ws;  ws += (size_t)N_NODES * sizeof(int);
    int* incl   = (int*)ws;  ws += (size_t)N_NODES * sizeof(int);
    int* off    = (int*)ws;  ws += (size_t)(N_NODES + 1) * sizeof(int);
    int* cursor = (int*)ws;  ws += (size_t)N_NODES * sizeof(int);
    int* bsum   = (int*)ws;  ws += (size_t)(NB_SCAN + 1) * sizeof(int);
    int* esrc   = (int*)ws;  ws += (size_t)ET * sizeof(int);

    const int splitGrid = (int)((ND / 4 + 255) / 256);
    const int wGrid     = (int)((WSZ + 255) / 256);
    const int edgeGrid  = (ET + 255) / 256;
    const int gemmGrid  = ((N_NODES + 127) / 128) * 2;   // rowBlocks x 2 col halves
    const int nodeGrid  = (N_NODES + 3) / 4;

    // prep (independent of CSR)
    split_x_kernel<<<splitGrid, 256, 0, stream>>>(x, hhi, hlo);
    prep_weights_kernel<<<wGrid, 256, 0, stream>>>(Wl, Wr, wlh, wll, wrh, wrl);

    // CSR build (hierarchical scan)
    hipMemsetAsync(deg, 0, (size_t)N_NODES * sizeof(int), stream);
    degree_kernel<<<edgeGrid, 256, 0, stream>>>(dstp, deg);
    scan1_kernel<<<NB_SCAN, 1024, 0, stream>>>(deg, incl, bsum);
    scan2_kernel<<<1, 64, 0, stream>>>(bsum);
    scan3_kernel<<<(N_NODES + 256) / 256, 256, 0, stream>>>(deg, incl, bsum, off, cursor);
    scatter_kernel<<<edgeGrid, 256, 0, stream>>>(srcp, dstp, cursor, esrc);

    for (int l = 0; l < NLAYERS; l++) {
        size_t wOff = (size_t)l * D * D;
        gemm_mfma_kernel<<<gemmGrid, 256, 0, stream>>>(
            hhi, hlo, wlh + wOff, wll + wOff, wrh + wOff, wrl + wOff,
            bl + (size_t)l * D, br + (size_t)l * D, xlb, xr, N_NODES);

        if (l == NLAYERS - 1) {
            node_attn_kernel<1><<<nodeGrid, 256, 0, stream>>>(
                xlb, xr, att + (size_t)l * D, bias + (size_t)l * D,
                off, esrc, out, nullptr, nullptr);
        } else {
            node_attn_kernel<0><<<nodeGrid, 256, 0, stream>>>(
                xlb, xr, att + (size_t)l * D, bias + (size_t)l * D,
                off, esrc, nullptr, hhi, hlo);
        }
    }
}

// Round 7
// 417.934 us; speedup vs baseline: 1.1437x; 1.1437x over previous
//
#include <hip/hip_runtime.h>
#include <cstdint>
#include <cstddef>

#define N_NODES 50000
#define N_EDGES 800000
#define ET (N_EDGES + N_NODES)   // edges + self loops
#define D 128
#define NLAYERS 3
#define SLOPE 0.2f
#define NB_SCAN ((N_NODES + 1023) / 1024)   // 49 blocks

typedef __bf16 bf16x8 __attribute__((ext_vector_type(8)));
typedef float  f32x4  __attribute__((ext_vector_type(4)));
typedef float  f32x2  __attribute__((ext_vector_type(2)));

// ---- bf16 split helpers (round-to-nearest-even) ----
__device__ __forceinline__ unsigned short f2bf_rne(float v) {
    unsigned u = __float_as_uint(v);
    u += 0x7fffu + ((u >> 16) & 1u);
    return (unsigned short)(u >> 16);
}
__device__ __forceinline__ float bf2f(unsigned short h) {
    return __uint_as_float(((unsigned)h) << 16);
}
// unpack packed pair of bf16 (lo in bits 0-15, hi in 16-31) -> f32x2
__device__ __forceinline__ f32x2 unpack_bf2(unsigned u) {
    f32x2 r;
    r.x = __uint_as_float(u << 16);
    r.y = __uint_as_float(u & 0xffff0000u);
    return r;
}

// ================= prep: split fp32 -> bf16 hi/lo ==================
__global__ void split_x_kernel(const float* __restrict__ x,
                               unsigned short* __restrict__ hhi,
                               unsigned short* __restrict__ hlo)
{
    int i = blockIdx.x * blockDim.x + threadIdx.x;   // float4 index
    if (i >= (N_NODES * D) / 4) return;
    float4 v = ((const float4*)x)[i];
    unsigned short h0 = f2bf_rne(v.x), h1 = f2bf_rne(v.y);
    unsigned short h2 = f2bf_rne(v.z), h3 = f2bf_rne(v.w);
    unsigned short l0 = f2bf_rne(v.x - bf2f(h0)), l1 = f2bf_rne(v.y - bf2f(h1));
    unsigned short l2 = f2bf_rne(v.z - bf2f(h2)), l3 = f2bf_rne(v.w - bf2f(h3));
    uint2 hw, lw;
    hw.x = (unsigned)h0 | ((unsigned)h1 << 16);
    hw.y = (unsigned)h2 | ((unsigned)h3 << 16);
    lw.x = (unsigned)l0 | ((unsigned)l1 << 16);
    lw.y = (unsigned)l2 | ((unsigned)l3 << 16);
    ((uint2*)hhi)[i] = hw;
    ((uint2*)hlo)[i] = lw;
}

// transpose + split weights: W[l][k][n] -> Wt[l][n][k] hi/lo for both mats
__global__ void prep_weights_kernel(const float* __restrict__ Wl,
                                    const float* __restrict__ Wr,
                                    unsigned short* __restrict__ wlh, unsigned short* __restrict__ wll,
                                    unsigned short* __restrict__ wrh, unsigned short* __restrict__ wrl)
{
    int idx = blockIdx.x * blockDim.x + threadIdx.x;
    if (idx >= NLAYERS * D * D) return;
    int l   = idx / (D * D);
    int rem = idx - l * D * D;
    int kk  = rem / D;
    int nn  = rem - kk * D;
    int tp  = l * D * D + nn * D + kk;
    float v = Wl[idx];
    unsigned short h = f2bf_rne(v);
    wlh[tp] = h;
    wll[tp] = f2bf_rne(v - bf2f(h));
    v = Wr[idx];
    h = f2bf_rne(v);
    wrh[tp] = h;
    wrl[tp] = f2bf_rne(v - bf2f(h));
}

// ================= CSR build ==================
__global__ void degree_kernel(const int* __restrict__ dstp, int* __restrict__ deg)
{
    int e = blockIdx.x * blockDim.x + threadIdx.x;
    if (e >= ET) return;
    int dt = (e < N_EDGES) ? dstp[e] : e - N_EDGES;
    atomicAdd(deg + dt, 1);
}

// hierarchical scan: per-block inclusive scan + block sums
__global__ void scan1_kernel(const int* __restrict__ deg,
                             int* __restrict__ incl, int* __restrict__ bsum)
{
    __shared__ int tmp[1024];
    int tid = threadIdx.x;
    int i = blockIdx.x * 1024 + tid;
    int v = (i < N_NODES) ? deg[i] : 0;
    tmp[tid] = v;
    __syncthreads();
    #pragma unroll
    for (int o = 1; o < 1024; o <<= 1) {
        int t = (tid >= o) ? tmp[tid - o] : 0;
        __syncthreads();
        tmp[tid] += t;
        __syncthreads();
    }
    if (i < N_NODES) incl[i] = tmp[tid];
    if (tid == 1023) bsum[blockIdx.x] = tmp[1023];
}

// one wave: exclusive scan of the NB_SCAN block sums (+ total at bsum[NB_SCAN])
__global__ void scan2_kernel(int* __restrict__ bsum)
{
    int lane = threadIdx.x;
    int v = (lane < NB_SCAN) ? bsum[lane] : 0;
    int orig = v;
    #pragma unroll
    for (int o = 1; o < 64; o <<= 1) {
        int t = __shfl_up(v, o, 64);
        if (lane >= o) v += t;
    }
    if (lane < NB_SCAN) bsum[lane] = v - orig;    // exclusive
    if (lane == 63)     bsum[NB_SCAN] = v;        // grand total
}

// finalize: off[] (exclusive global) and cursor[] copy
__global__ void scan3_kernel(const int* __restrict__ deg, const int* __restrict__ incl,
                             const int* __restrict__ bsum,
                             int* __restrict__ off, int* __restrict__ cursor)
{
    int i = blockIdx.x * blockDim.x + threadIdx.x;
    if (i < N_NODES) {
        int e = incl[i] - deg[i] + bsum[i >> 10];
        off[i] = e;
        cursor[i] = e;
    } else if (i == N_NODES) {
        off[N_NODES] = bsum[NB_SCAN];
    }
}

__global__ void scatter_kernel(const int* __restrict__ srcp, const int* __restrict__ dstp,
                               int* __restrict__ cursor, int* __restrict__ esrc)
{
    int e = blockIdx.x * blockDim.x + threadIdx.x;
    if (e >= ET) return;
    int s, dt;
    if (e < N_EDGES) { s = srcp[e]; dt = dstp[e]; }
    else             { s = e - N_EDGES; dt = s; }
    int pos = atomicAdd(cursor + dt, 1);
    esrc[pos] = s;
}

// ============ MFMA dual GEMM, 3-term bf16x2, register-blocked + B double-buffer ======
// Wave tile: 32 rows x 64 cols. Block = 4 waves = 128 rows; grid = rowBlocks x 2 colHalves.
#define LOADB(BLH, BLL, BRH, BRL, n0)                                     \
    {   size_t boff = (size_t)((n0) + gl) * D + kg * 8;                   \
        _Pragma("unroll")                                                 \
        for (int ks = 0; ks < 4; ks++) {                                  \
            BLH[ks] = *(const bf16x8*)(wlh + boff + ks * 32);             \
            BLL[ks] = *(const bf16x8*)(wll + boff + ks * 32);             \
            BRH[ks] = *(const bf16x8*)(wrh + boff + ks * 32);             \
            BRL[ks] = *(const bf16x8*)(wrl + boff + ks * 32);             \
        } }

#define COMPUTE(BLH, BLL, BRH, BRL, n0)                                              \
    {   f32x4 accl0 = {0.f,0.f,0.f,0.f}, accr0 = {0.f,0.f,0.f,0.f};                  \
        f32x4 accl1 = {0.f,0.f,0.f,0.f}, accr1 = {0.f,0.f,0.f,0.f};                  \
        _Pragma("unroll")                                                            \
        for (int ks = 0; ks < 4; ks++) {                                             \
            accl0 = __builtin_amdgcn_mfma_f32_16x16x32_bf16(Ah0[ks], BLH[ks], accl0, 0, 0, 0); \
            accl0 = __builtin_amdgcn_mfma_f32_16x16x32_bf16(Al0[ks], BLH[ks], accl0, 0, 0, 0); \
            accl0 = __builtin_amdgcn_mfma_f32_16x16x32_bf16(Ah0[ks], BLL[ks], accl0, 0, 0, 0); \
            accr0 = __builtin_amdgcn_mfma_f32_16x16x32_bf16(Ah0[ks], BRH[ks], accr0, 0, 0, 0); \
            accr0 = __builtin_amdgcn_mfma_f32_16x16x32_bf16(Al0[ks], BRH[ks], accr0, 0, 0, 0); \
            accr0 = __builtin_amdgcn_mfma_f32_16x16x32_bf16(Ah0[ks], BRL[ks], accr0, 0, 0, 0); \
            accl1 = __builtin_amdgcn_mfma_f32_16x16x32_bf16(Ah1[ks], BLH[ks], accl1, 0, 0, 0); \
            accl1 = __builtin_amdgcn_mfma_f32_16x16x32_bf16(Al1[ks], BLH[ks], accl1, 0, 0, 0); \
            accl1 = __builtin_amdgcn_mfma_f32_16x16x32_bf16(Ah1[ks], BLL[ks], accl1, 0, 0, 0); \
            accr1 = __builtin_amdgcn_mfma_f32_16x16x32_bf16(Ah1[ks], BRH[ks], accr1, 0, 0, 0); \
            accr1 = __builtin_amdgcn_mfma_f32_16x16x32_bf16(Al1[ks], BRH[ks], accr1, 0, 0, 0); \
            accr1 = __builtin_amdgcn_mfma_f32_16x16x32_bf16(Ah1[ks], BRL[ks], accr1, 0, 0, 0); \
        }                                                                            \
        float blc = bl[(n0) + gl], brc = br[(n0) + gl];                              \
        _Pragma("unroll")                                                            \
        for (int r = 0; r < 4; r++) {                                                \
            int row0 = m0 + kg * 4 + r;                                              \
            if (row0 < n) {                                                          \
                xlb[(size_t)row0 * D + (n0) + gl] = f2bf_rne(accl0[r] + blc);        \
                xr [(size_t)row0 * D + (n0) + gl] = accr0[r] + brc;                  \
            }                                                                        \
            int row1 = m0 + 16 + kg * 4 + r;                                         \
            if (row1 < n) {                                                          \
                xlb[(size_t)row1 * D + (n0) + gl] = f2bf_rne(accl1[r] + blc);        \
                xr [(size_t)row1 * D + (n0) + gl] = accr1[r] + brc;                  \
            }                                                                        \
        } }

__global__ __launch_bounds__(256, 2)
void gemm_mfma_kernel(const unsigned short* __restrict__ hhi,
                      const unsigned short* __restrict__ hlo,
                      const unsigned short* __restrict__ wlh,
                      const unsigned short* __restrict__ wll,
                      const unsigned short* __restrict__ wrh,
                      const unsigned short* __restrict__ wrl,
                      const float* __restrict__ bl, const float* __restrict__ br,
                      unsigned short* __restrict__ xlb, float* __restrict__ xr, int n)
{
    int lane = threadIdx.x & 63;
    int wid  = threadIdx.x >> 6;          // 0..3
    int rowB = blockIdx.x >> 1;
    int c0   = (blockIdx.x & 1) * 64;     // column half
    int m0   = (rowB * 4 + wid) * 32;     // this wave's 32 rows
    if (m0 >= n) return;
    int gl = lane & 15;
    int kg = lane >> 4;

    // A fragments: 2 row-tiles x 4 ks x hi/lo, held in registers for the whole kernel
    int ar0 = m0 + gl;      if (ar0 >= n) ar0 = n - 1;
    int ar1 = m0 + 16 + gl; if (ar1 >= n) ar1 = n - 1;
    const unsigned short* ah0 = hhi + (size_t)ar0 * D + kg * 8;
    const unsigned short* al0 = hlo + (size_t)ar0 * D + kg * 8;
    const unsigned short* ah1 = hhi + (size_t)ar1 * D + kg * 8;
    const unsigned short* al1 = hlo + (size_t)ar1 * D + kg * 8;
    bf16x8 Ah0[4], Al0[4], Ah1[4], Al1[4];
    #pragma unroll
    for (int ks = 0; ks < 4; ks++) {
        Ah0[ks] = *(const bf16x8*)(ah0 + ks * 32);
        Al0[ks] = *(const bf16x8*)(al0 + ks * 32);
        Ah1[ks] = *(const bf16x8*)(ah1 + ks * 32);
        Al1[ks] = *(const bf16x8*)(al1 + ks * 32);
    }

    // B ping-pong buffers: compute nt with one while prefetching nt+1 into the other
    bf16x8 B0lh[4], B0ll[4], B0rh[4], B0rl[4];
    bf16x8 B1lh[4], B1ll[4], B1rh[4], B1rl[4];

    LOADB(B0lh, B0ll, B0rh, B0rl, c0);
    LOADB(B1lh, B1ll, B1rh, B1rl, c0 + 16);
    COMPUTE(B0lh, B0ll, B0rh, B0rl, c0);
    LOADB(B0lh, B0ll, B0rh, B0rl, c0 + 32);
    COMPUTE(B1lh, B1ll, B1rh, B1rl, c0 + 16);
    LOADB(B1lh, B1ll, B1rh, B1rl, c0 + 48);
    COMPUTE(B0lh, B0ll, B0rh, B0rl, c0 + 32);
    COMPUTE(B1lh, B1ll, B1rh, B1rl, c0 + 48);
}

// ============ fused per-node GATv2: 4 edges/wave, 16 lanes/edge, packed f32x2 ========
// defer-max online softmax (THR=8): common path has no acc rescale.
// LAST=1: fuse log_softmax, write fp32 out. LAST=0: write h as bf16 hi/lo.
template <int LAST>
__global__ void node_attn_kernel(const unsigned short* __restrict__ xlb,
                                 const float* __restrict__ xr,
                                 const float* __restrict__ att,
                                 const float* __restrict__ bias,
                                 const int* __restrict__ off,
                                 const int* __restrict__ esrc,
                                 float* __restrict__ outF,
                                 unsigned short* __restrict__ hhi,
                                 unsigned short* __restrict__ hlo)
{
    int i    = (int)((blockIdx.x * (size_t)blockDim.x + threadIdx.x) >> 6);
    int lane = threadIdx.x & 63;
    if (i >= N_NODES) return;
    int g  = lane >> 4;     // edge slot 0..3
    int gl = lane & 15;     // lane within group
    int fb = gl * 8;        // this lane's 8 features (4 f32x2)

    f32x2 aa[4], rr[4];
    {
        float4 a0 = *(const float4*)(att + fb);
        float4 a1 = *(const float4*)(att + fb + 4);
        const float* xri = xr + (size_t)i * D + fb;
        float4 r0 = *(const float4*)(xri);
        float4 r1 = *(const float4*)(xri + 4);
        aa[0] = (f32x2){a0.x, a0.y}; aa[1] = (f32x2){a0.z, a0.w};
        aa[2] = (f32x2){a1.x, a1.y}; aa[3] = (f32x2){a1.z, a1.w};
        rr[0] = (f32x2){r0.x, r0.y}; rr[1] = (f32x2){r0.z, r0.w};
        rr[2] = (f32x2){r1.x, r1.y}; rr[3] = (f32x2){r1.z, r1.w};
    }

    float m = -1e30f, l = 0.f;
    f32x2 acc[4];
    #pragma unroll
    for (int j = 0; j < 4; j++) acc[j] = (f32x2){0.f, 0.f};

    int k    = off[i];
    int kEnd = off[i + 1];

    int kk = k + g;
    bool valid = kk < kEnd;
    int s0 = esrc[valid ? kk : kEnd - 1];
    uint4 x4 = *(const uint4*)(xlb + (size_t)s0 * D + fb);

    while (k < kEnd) {
        int kn = k + 4;
        uint4 nx4 = x4;
        bool nvalid = false;
        if (kn < kEnd) {                       // wave-uniform branch: prefetch
            int nkk = kn + g;
            nvalid = nkk < kEnd;
            int ns = esrc[nvalid ? nkk : kEnd - 1];
            nx4 = *(const uint4*)(xlb + (size_t)ns * D + fb);
        }
        // unpack 8 bf16 -> 4 f32x2
        f32x2 xx[4];
        xx[0] = unpack_bf2(x4.x); xx[1] = unpack_bf2(x4.y);
        xx[2] = unpack_bf2(x4.z); xx[3] = unpack_bf2(x4.w);
        // packed score partial: att . leaky_relu(x + r)
        f32x2 sc2 = {0.f, 0.f};
        #pragma unroll
        for (int j = 0; j < 4; j++) {
            f32x2 v  = xx[j] + rr[j];
            f32x2 lv = __builtin_elementwise_max(v, v * SLOPE);
            sc2 = sc2 + lv * aa[j];
        }
        float sc = sc2.x + sc2.y;
        sc += __shfl_xor(sc, 1, 64);
        sc += __shfl_xor(sc, 2, 64);
        sc += __shfl_xor(sc, 4, 64);
        sc += __shfl_xor(sc, 8, 64);
        // defer-max online softmax
        if (__any(sc > m + 8.f)) {
            // rare path: rescale (groups with no growth get f~1, harmless)
            float mn = fmaxf(m, sc);
            float f  = __expf(m - mn);
            float p  = valid ? __expf(sc - mn) : 0.f;
            l = l * f + p;
            f32x2 fv = {f, f}, pv = {p, p};
            #pragma unroll
            for (int j = 0; j < 4; j++) acc[j] = acc[j] * fv + xx[j] * pv;
            m = mn;
        } else {
            // common path: no rescale
            float p = valid ? __expf(sc - m) : 0.f;
            l += p;
            f32x2 pv = {p, p};
            #pragma unroll
            for (int j = 0; j < 4; j++) acc[j] = acc[j] + xx[j] * pv;
        }
        x4 = nx4; valid = nvalid;
        k = kn;
    }

    // merge the 4 groups' online-softmax states (xor 16, then 32)
    #pragma unroll
    for (int o = 16; o <= 32; o <<= 1) {
        float mo  = __shfl_xor(m, o, 64);
        float lo2 = __shfl_xor(l, o, 64);
        float mn  = fmaxf(m, mo);
        float f1  = __expf(m - mn);
        float f2s = __expf(mo - mn);
        l = l * f1 + lo2 * f2s;
        f32x2 f1v = {f1, f1}, f2v = {f2s, f2s};
        #pragma unroll
        for (int j = 0; j < 4; j++) {
            f32x2 ao;
            ao.x = __shfl_xor(acc[j].x, o, 64);
            ao.y = __shfl_xor(acc[j].y, o, 64);
            acc[j] = acc[j] * f1v + ao * f2v;
        }
        m = mn;
    }

    float inv = 1.f / (l + 1e-16f);
    f32x2 hv[4];
    {
        float4 b0 = *(const float4*)(bias + fb);
        float4 b1 = *(const float4*)(bias + fb + 4);
        f32x2 iv = {inv, inv}, z = {0.f, 0.f};
        f32x2 bb0 = {b0.x, b0.y}, bb1 = {b0.z, b0.w};
        f32x2 bb2 = {b1.x, b1.y}, bb3 = {b1.z, b1.w};
        hv[0] = __builtin_elementwise_max(acc[0] * iv + bb0, z);
        hv[1] = __builtin_elementwise_max(acc[1] * iv + bb1, z);
        hv[2] = __builtin_elementwise_max(acc[2] * iv + bb2, z);
        hv[3] = __builtin_elementwise_max(acc[3] * iv + bb3, z);
    }

    if (LAST) {
        float mx = fmaxf(hv[0].x, hv[0].y);
        #pragma unroll
        for (int j = 1; j < 4; j++) mx = fmaxf(mx, fmaxf(hv[j].x, hv[j].y));
        mx = fmaxf(mx, __shfl_xor(mx, 1, 64));
        mx = fmaxf(mx, __shfl_xor(mx, 2, 64));
        mx = fmaxf(mx, __shfl_xor(mx, 4, 64));
        mx = fmaxf(mx, __shfl_xor(mx, 8, 64));
        float se = 0.f;
        #pragma unroll
        for (int j = 0; j < 4; j++) se += __expf(hv[j].x - mx) + __expf(hv[j].y - mx);
        se += __shfl_xor(se, 1, 64);
        se += __shfl_xor(se, 2, 64);
        se += __shfl_xor(se, 4, 64);
        se += __shfl_xor(se, 8, 64);
        float ls = logf(se) + mx;
        if (g == 0) {
            float4 o0 = make_float4(hv[0].x - ls, hv[0].y - ls, hv[1].x - ls, hv[1].y - ls);
            float4 o1 = make_float4(hv[2].x - ls, hv[2].y - ls, hv[3].x - ls, hv[3].y - ls);
            float* dst = outF + (size_t)i * D + fb;
            *(float4*)(dst)     = o0;
            *(float4*)(dst + 4) = o1;
        }
    } else {
        if (g < 2) {
            unsigned pk[4];
            #pragma unroll
            for (int j = 0; j < 4; j++) {
                float v0 = hv[j].x, v1 = hv[j].y;
                unsigned short h0 = f2bf_rne(v0), h1 = f2bf_rne(v1);
                if (g == 0) pk[j] = (unsigned)h0 | ((unsigned)h1 << 16);
                else {
                    unsigned short l0 = f2bf_rne(v0 - bf2f(h0));
                    unsigned short l1 = f2bf_rne(v1 - bf2f(h1));
                    pk[j] = (unsigned)l0 | ((unsigned)l1 << 16);
                }
            }
            unsigned short* dst = (g == 0 ? hhi : hlo) + (size_t)i * D + fb;
            *(uint4*)dst = make_uint4(pk[0], pk[1], pk[2], pk[3]);
        }
    }
}

extern "C" void kernel_launch(void* const* d_in, const int* in_sizes, int n_in,
                              void* d_out, int out_size, void* d_ws, size_t ws_size,
                              hipStream_t stream)
{
    const float* x    = (const float*)d_in[0];
    const int*   ei   = (const int*)  d_in[1];
    const float* Wl   = (const float*)d_in[2];
    const float* bl   = (const float*)d_in[3];
    const float* Wr   = (const float*)d_in[4];
    const float* br   = (const float*)d_in[5];
    const float* att  = (const float*)d_in[6];
    const float* bias = (const float*)d_in[7];
    float* out = (float*)d_out;

    const int* srcp = ei;
    const int* dstp = ei + N_EDGES;

    const size_t ND = (size_t)N_NODES * D;
    const size_t WSZ = (size_t)NLAYERS * D * D;
    char* ws = (char*)d_ws;
    unsigned short* xlb = (unsigned short*)ws; ws += ND * sizeof(unsigned short);
    float* xr  = (float*)ws;                   ws += ND * sizeof(float);
    unsigned short* hhi = (unsigned short*)ws; ws += ND * sizeof(unsigned short);
    unsigned short* hlo = (unsigned short*)ws; ws += ND * sizeof(unsigned short);
    unsigned short* wlh = (unsigned short*)ws; ws += WSZ * sizeof(unsigned short);
    unsigned short* wll = (unsigned short*)ws; ws += WSZ * sizeof(unsigned short);
    unsigned short* wrh = (unsigned short*)ws; ws += WSZ * sizeof(unsigned short);
    unsigned short* wrl = (unsigned short*)ws; ws += WSZ * sizeof(unsigned short);
    int* deg    = (int*)ws;  ws += (size_t)N_NODES * sizeof(int);
    int* incl   = (int*)ws;  ws += (size_t)N_NODES * sizeof(int);
    int* off    = (int*)ws;  ws += (size_t)(N_NODES + 1) * sizeof(int);
    int* cursor = (int*)ws;  ws += (size_t)N_NODES * sizeof(int);
    int* bsum   = (int*)ws;  ws += (size_t)(NB_SCAN + 1) * sizeof(int);
    int* esrc   = (int*)ws;  ws += (size_t)ET * sizeof(int);

    const int splitGrid = (int)((ND / 4 + 255) / 256);
    const int wGrid     = (int)((WSZ + 255) / 256);
    const int edgeGrid  = (ET + 255) / 256;
    const int gemmGrid  = ((N_NODES + 127) / 128) * 2;   // rowBlocks x 2 col halves
    const int nodeGrid  = (N_NODES + 3) / 4;

    // prep (independent of CSR)
    split_x_kernel<<<splitGrid, 256, 0, stream>>>(x, hhi, hlo);
    prep_weights_kernel<<<wGrid, 256, 0, stream>>>(Wl, Wr, wlh, wll, wrh, wrl);

    // CSR build (hierarchical scan)
    hipMemsetAsync(deg, 0, (size_t)N_NODES * sizeof(int), stream);
    degree_kernel<<<edgeGrid, 256, 0, stream>>>(dstp, deg);
    scan1_kernel<<<NB_SCAN, 1024, 0, stream>>>(deg, incl, bsum);
    scan2_kernel<<<1, 64, 0, stream>>>(bsum);
    scan3_kernel<<<(N_NODES + 256) / 256, 256, 0, stream>>>(deg, incl, bsum, off, cursor);
    scatter_kernel<<<edgeGrid, 256, 0, stream>>>(srcp, dstp, cursor, esrc);

    for (int l = 0; l < NLAYERS; l++) {
        size_t wOff = (size_t)l * D * D;
        gemm_mfma_kernel<<<gemmGrid, 256, 0, stream>>>(
            hhi, hlo, wlh + wOff, wll + wOff, wrh + wOff, wrl + wOff,
            bl + (size_t)l * D, br + (size_t)l * D, xlb, xr, N_NODES);

        if (l == NLAYERS - 1) {
            node_attn_kernel<1><<<nodeGrid, 256, 0, stream>>>(
                xlb, xr, att + (size_t)l * D, bias + (size_t)l * D,
                off, esrc, out, nullptr, nullptr);
        } else {
            node_attn_kernel<0><<<nodeGrid, 256, 0, stream>>>(
                xlb, xr, att + (size_t)l * D, bias + (size_t)l * D,
                off, esrc, nullptr, hhi, hlo);
        }
    }
}

// Round 8
// 375.157 us; speedup vs baseline: 1.2741x; 1.1140x over previous
//
#include <hip/hip_runtime.h>
#include <cstdint>
#include <cstddef>

#define N_NODES 50000
#define N_EDGES 800000
#define ET (N_EDGES + N_NODES)   // edges + self loops
#define D 128
#define NLAYERS 3
#define SLOPE 0.2f
#define NB_SCAN ((N_NODES + 1023) / 1024)   // 49 blocks

typedef __bf16 bf16x8 __attribute__((ext_vector_type(8)));
typedef float  f32x4  __attribute__((ext_vector_type(4)));
typedef float  f32x2  __attribute__((ext_vector_type(2)));

// ---- bf16 split helpers (round-to-nearest-even) ----
__device__ __forceinline__ unsigned short f2bf_rne(float v) {
    unsigned u = __float_as_uint(v);
    u += 0x7fffu + ((u >> 16) & 1u);
    return (unsigned short)(u >> 16);
}
__device__ __forceinline__ float bf2f(unsigned short h) {
    return __uint_as_float(((unsigned)h) << 16);
}
__device__ __forceinline__ f32x2 unpack_bf2(unsigned u) {
    f32x2 r;
    r.x = __uint_as_float(u << 16);
    r.y = __uint_as_float(u & 0xffff0000u);
    return r;
}

// ============ merged prep: split x -> bf16 hi/lo, transpose+split weights, zero deg ==
// weights: W[l][k][n] -> Wt[l][n][k]; wl as hi+lo (3-term path), wr hi only (score-only)
__global__ void prep_kernel(const float* __restrict__ x,
                            const float* __restrict__ Wl,
                            const float* __restrict__ Wr,
                            unsigned short* __restrict__ hhi,
                            unsigned short* __restrict__ hlo,
                            unsigned short* __restrict__ wlh,
                            unsigned short* __restrict__ wll,
                            unsigned short* __restrict__ wrh,
                            int* __restrict__ deg)
{
    int idx = blockIdx.x * blockDim.x + threadIdx.x;
    if (idx < (N_NODES * D) / 4) {
        float4 v = ((const float4*)x)[idx];
        unsigned short h0 = f2bf_rne(v.x), h1 = f2bf_rne(v.y);
        unsigned short h2 = f2bf_rne(v.z), h3 = f2bf_rne(v.w);
        unsigned short l0 = f2bf_rne(v.x - bf2f(h0)), l1 = f2bf_rne(v.y - bf2f(h1));
        unsigned short l2 = f2bf_rne(v.z - bf2f(h2)), l3 = f2bf_rne(v.w - bf2f(h3));
        uint2 hw, lw;
        hw.x = (unsigned)h0 | ((unsigned)h1 << 16);
        hw.y = (unsigned)h2 | ((unsigned)h3 << 16);
        lw.x = (unsigned)l0 | ((unsigned)l1 << 16);
        lw.y = (unsigned)l2 | ((unsigned)l3 << 16);
        ((uint2*)hhi)[idx] = hw;
        ((uint2*)hlo)[idx] = lw;
    }
    if (idx < NLAYERS * D * D) {
        int l   = idx / (D * D);
        int rem = idx - l * D * D;
        int kk  = rem / D;
        int nn  = rem - kk * D;
        int tp  = l * D * D + nn * D + kk;
        float v = Wl[idx];
        unsigned short h = f2bf_rne(v);
        wlh[tp] = h;
        wll[tp] = f2bf_rne(v - bf2f(h));
        wrh[tp] = f2bf_rne(Wr[idx]);
    }
    if (idx < N_NODES) deg[idx] = 0;
}

// ================= CSR build ==================
__global__ void degree_kernel(const int* __restrict__ dstp, int* __restrict__ deg)
{
    int e = blockIdx.x * blockDim.x + threadIdx.x;
    if (e >= ET) return;
    int dt = (e < N_EDGES) ? dstp[e] : e - N_EDGES;
    atomicAdd(deg + dt, 1);
}

// per-block inclusive scan + block sums
__global__ void scan1_kernel(const int* __restrict__ deg,
                             int* __restrict__ incl, int* __restrict__ bsum)
{
    __shared__ int tmp[1024];
    int tid = threadIdx.x;
    int i = blockIdx.x * 1024 + tid;
    int v = (i < N_NODES) ? deg[i] : 0;
    tmp[tid] = v;
    __syncthreads();
    #pragma unroll
    for (int o = 1; o < 1024; o <<= 1) {
        int t = (tid >= o) ? tmp[tid - o] : 0;
        __syncthreads();
        tmp[tid] += t;
        __syncthreads();
    }
    if (i < N_NODES) incl[i] = tmp[tid];
    if (tid == 1023) bsum[blockIdx.x] = tmp[1023];
}

// finalize: each block wave-scans the 49 block sums locally (kills the scan2 dispatch),
// then writes off[] (exclusive global) and cursor[].
__global__ void scan3_kernel(const int* __restrict__ deg, const int* __restrict__ incl,
                             const int* __restrict__ bsum,
                             int* __restrict__ off, int* __restrict__ cursor)
{
    __shared__ int sb[NB_SCAN + 1];
    int tid = threadIdx.x;
    if (tid < 64) {
        int v = (tid < NB_SCAN) ? bsum[tid] : 0;
        int orig = v;
        #pragma unroll
        for (int o = 1; o < 64; o <<= 1) {
            int t = __shfl_up(v, o, 64);
            if (tid >= o) v += t;
        }
        if (tid < NB_SCAN) sb[tid] = v - orig;   // exclusive
        if (tid == 63)     sb[NB_SCAN] = v;      // grand total
    }
    __syncthreads();
    int i = blockIdx.x * blockDim.x + tid;
    if (i < N_NODES) {
        int e = incl[i] - deg[i] + sb[i >> 10];
        off[i] = e;
        cursor[i] = e;
    } else if (i == N_NODES) {
        off[N_NODES] = sb[NB_SCAN];
    }
}

__global__ void scatter_kernel(const int* __restrict__ srcp, const int* __restrict__ dstp,
                               int* __restrict__ cursor, int* __restrict__ esrc)
{
    int e = blockIdx.x * blockDim.x + threadIdx.x;
    if (e >= ET) return;
    int s, dt;
    if (e < N_EDGES) { s = srcp[e]; dt = dstp[e]; }
    else             { s = e - N_EDGES; dt = s; }
    int pos = atomicAdd(cursor + dt, 1);
    esrc[pos] = s;
}

// ============ MFMA dual GEMM: xl 3-term bf16x2 (~fp32), xr single-term bf16 ==========
// Wave tile: 32 rows x 64 cols. Block = 4 waves = 128 rows; grid = rowBlocks x 2 colHalves.
// Bias hoisted to prologue (was a per-tile L2-latency stall before the stores).
#define LOADB(BLH, BLL, BRH, n0)                                          \
    {   size_t boff = (size_t)((n0) + gl) * D + kg * 8;                   \
        _Pragma("unroll")                                                 \
        for (int ks = 0; ks < 4; ks++) {                                  \
            BLH[ks] = *(const bf16x8*)(wlh + boff + ks * 32);             \
            BLL[ks] = *(const bf16x8*)(wll + boff + ks * 32);             \
            BRH[ks] = *(const bf16x8*)(wrh + boff + ks * 32);             \
        } }

#define COMPUTE(BLH, BLL, BRH, t)                                                    \
    {   const int n0 = c0 + (t) * 16;                                                \
        f32x4 accl0 = {0.f,0.f,0.f,0.f}, accr0 = {0.f,0.f,0.f,0.f};                  \
        f32x4 accl1 = {0.f,0.f,0.f,0.f}, accr1 = {0.f,0.f,0.f,0.f};                  \
        _Pragma("unroll")                                                            \
        for (int ks = 0; ks < 4; ks++) {                                             \
            accl0 = __builtin_amdgcn_mfma_f32_16x16x32_bf16(Ah0[ks], BLH[ks], accl0, 0, 0, 0); \
            accl0 = __builtin_amdgcn_mfma_f32_16x16x32_bf16(Al0[ks], BLH[ks], accl0, 0, 0, 0); \
            accl0 = __builtin_amdgcn_mfma_f32_16x16x32_bf16(Ah0[ks], BLL[ks], accl0, 0, 0, 0); \
            accr0 = __builtin_amdgcn_mfma_f32_16x16x32_bf16(Ah0[ks], BRH[ks], accr0, 0, 0, 0); \
            accl1 = __builtin_amdgcn_mfma_f32_16x16x32_bf16(Ah1[ks], BLH[ks], accl1, 0, 0, 0); \
            accl1 = __builtin_amdgcn_mfma_f32_16x16x32_bf16(Al1[ks], BLH[ks], accl1, 0, 0, 0); \
            accl1 = __builtin_amdgcn_mfma_f32_16x16x32_bf16(Ah1[ks], BLL[ks], accl1, 0, 0, 0); \
            accr1 = __builtin_amdgcn_mfma_f32_16x16x32_bf16(Ah1[ks], BRH[ks], accr1, 0, 0, 0); \
        }                                                                            \
        _Pragma("unroll")                                                            \
        for (int r = 0; r < 4; r++) {                                                \
            int row0 = m0 + kg * 4 + r;                                              \
            if (row0 < n) {                                                          \
                xlb[(size_t)row0 * D + n0 + gl] = f2bf_rne(accl0[r] + blc[t]);       \
                xr [(size_t)row0 * D + n0 + gl] = accr0[r] + brc[t];                 \
            }                                                                        \
            int row1 = m0 + 16 + kg * 4 + r;                                         \
            if (row1 < n) {                                                          \
                xlb[(size_t)row1 * D + n0 + gl] = f2bf_rne(accl1[r] + blc[t]);       \
                xr [(size_t)row1 * D + n0 + gl] = accr1[r] + brc[t];                 \
            }                                                                        \
        } }

__global__ __launch_bounds__(256, 2)
void gemm_mfma_kernel(const unsigned short* __restrict__ hhi,
                      const unsigned short* __restrict__ hlo,
                      const unsigned short* __restrict__ wlh,
                      const unsigned short* __restrict__ wll,
                      const unsigned short* __restrict__ wrh,
                      const float* __restrict__ bl, const float* __restrict__ br,
                      unsigned short* __restrict__ xlb, float* __restrict__ xr, int n)
{
    int lane = threadIdx.x & 63;
    int wid  = threadIdx.x >> 6;          // 0..3
    int rowB = blockIdx.x >> 1;
    int c0   = (blockIdx.x & 1) * 64;     // column half
    int m0   = (rowB * 4 + wid) * 32;     // this wave's 32 rows
    if (m0 >= n) return;
    int gl = lane & 15;
    int kg = lane >> 4;

    // bias prologue (issue early; consumed only in the epilogue stores)
    float blc[4], brc[4];
    #pragma unroll
    for (int t = 0; t < 4; t++) {
        blc[t] = bl[c0 + t * 16 + gl];
        brc[t] = br[c0 + t * 16 + gl];
    }

    // A fragments: 2 row-tiles x 4 ks x hi/lo, register-resident
    int ar0 = m0 + gl;      if (ar0 >= n) ar0 = n - 1;
    int ar1 = m0 + 16 + gl; if (ar1 >= n) ar1 = n - 1;
    const unsigned short* ah0 = hhi + (size_t)ar0 * D + kg * 8;
    const unsigned short* al0 = hlo + (size_t)ar0 * D + kg * 8;
    const unsigned short* ah1 = hhi + (size_t)ar1 * D + kg * 8;
    const unsigned short* al1 = hlo + (size_t)ar1 * D + kg * 8;
    bf16x8 Ah0[4], Al0[4], Ah1[4], Al1[4];
    #pragma unroll
    for (int ks = 0; ks < 4; ks++) {
        Ah0[ks] = *(const bf16x8*)(ah0 + ks * 32);
        Al0[ks] = *(const bf16x8*)(al0 + ks * 32);
        Ah1[ks] = *(const bf16x8*)(ah1 + ks * 32);
        Al1[ks] = *(const bf16x8*)(al1 + ks * 32);
    }

    // B ping-pong: prefetch tile t+1 while computing tile t
    bf16x8 B0lh[4], B0ll[4], B0rh[4];
    bf16x8 B1lh[4], B1ll[4], B1rh[4];

    LOADB(B0lh, B0ll, B0rh, c0);
    LOADB(B1lh, B1ll, B1rh, c0 + 16);
    COMPUTE(B0lh, B0ll, B0rh, 0);
    LOADB(B0lh, B0ll, B0rh, c0 + 32);
    COMPUTE(B1lh, B1ll, B1rh, 1);
    LOADB(B1lh, B1ll, B1rh, c0 + 48);
    COMPUTE(B0lh, B0ll, B0rh, 2);
    COMPUTE(B1lh, B1ll, B1rh, 3);
}

// ============ fused per-node GATv2: 4 edges/wave, 16 lanes/edge, packed f32x2 ========
// defer-max online softmax (THR=8): common path has no acc rescale.
// LAST=1: fuse log_softmax, write fp32 out. LAST=0: write h as bf16 hi/lo.
template <int LAST>
__global__ void node_attn_kernel(const unsigned short* __restrict__ xlb,
                                 const float* __restrict__ xr,
                                 const float* __restrict__ att,
                                 const float* __restrict__ bias,
                                 const int* __restrict__ off,
                                 const int* __restrict__ esrc,
                                 float* __restrict__ outF,
                                 unsigned short* __restrict__ hhi,
                                 unsigned short* __restrict__ hlo)
{
    int i    = (int)((blockIdx.x * (size_t)blockDim.x + threadIdx.x) >> 6);
    int lane = threadIdx.x & 63;
    if (i >= N_NODES) return;
    int g  = lane >> 4;     // edge slot 0..3
    int gl = lane & 15;     // lane within group
    int fb = gl * 8;        // this lane's 8 features (4 f32x2)

    f32x2 aa[4], rr[4];
    {
        float4 a0 = *(const float4*)(att + fb);
        float4 a1 = *(const float4*)(att + fb + 4);
        const float* xri = xr + (size_t)i * D + fb;
        float4 r0 = *(const float4*)(xri);
        float4 r1 = *(const float4*)(xri + 4);
        aa[0] = (f32x2){a0.x, a0.y}; aa[1] = (f32x2){a0.z, a0.w};
        aa[2] = (f32x2){a1.x, a1.y}; aa[3] = (f32x2){a1.z, a1.w};
        rr[0] = (f32x2){r0.x, r0.y}; rr[1] = (f32x2){r0.z, r0.w};
        rr[2] = (f32x2){r1.x, r1.y}; rr[3] = (f32x2){r1.z, r1.w};
    }

    float m = -1e30f, l = 0.f;
    f32x2 acc[4];
    #pragma unroll
    for (int j = 0; j < 4; j++) acc[j] = (f32x2){0.f, 0.f};

    int k    = off[i];
    int kEnd = off[i + 1];

    int kk = k + g;
    bool valid = kk < kEnd;
    int s0 = esrc[valid ? kk : kEnd - 1];
    uint4 x4 = *(const uint4*)(xlb + (size_t)s0 * D + fb);

    while (k < kEnd) {
        int kn = k + 4;
        uint4 nx4 = x4;
        bool nvalid = false;
        if (kn < kEnd) {                       // wave-uniform branch: prefetch
            int nkk = kn + g;
            nvalid = nkk < kEnd;
            int ns = esrc[nvalid ? nkk : kEnd - 1];
            nx4 = *(const uint4*)(xlb + (size_t)ns * D + fb);
        }
        // unpack 8 bf16 -> 4 f32x2
        f32x2 xx[4];
        xx[0] = unpack_bf2(x4.x); xx[1] = unpack_bf2(x4.y);
        xx[2] = unpack_bf2(x4.z); xx[3] = unpack_bf2(x4.w);
        // packed score partial: att . leaky_relu(x + r)
        f32x2 sc2 = {0.f, 0.f};
        #pragma unroll
        for (int j = 0; j < 4; j++) {
            f32x2 v  = xx[j] + rr[j];
            f32x2 lv = __builtin_elementwise_max(v, v * SLOPE);
            sc2 = sc2 + lv * aa[j];
        }
        float sc = sc2.x + sc2.y;
        sc += __shfl_xor(sc, 1, 64);
        sc += __shfl_xor(sc, 2, 64);
        sc += __shfl_xor(sc, 4, 64);
        sc += __shfl_xor(sc, 8, 64);
        // defer-max online softmax
        if (__any(sc > m + 8.f)) {
            float mn = fmaxf(m, sc);
            float f  = __expf(m - mn);
            float p  = valid ? __expf(sc - mn) : 0.f;
            l = l * f + p;
            f32x2 fv = {f, f}, pv = {p, p};
            #pragma unroll
            for (int j = 0; j < 4; j++) acc[j] = acc[j] * fv + xx[j] * pv;
            m = mn;
        } else {
            float p = valid ? __expf(sc - m) : 0.f;
            l += p;
            f32x2 pv = {p, p};
            #pragma unroll
            for (int j = 0; j < 4; j++) acc[j] = acc[j] + xx[j] * pv;
        }
        x4 = nx4; valid = nvalid;
        k = kn;
    }

    // merge the 4 groups' online-softmax states (xor 16, then 32)
    #pragma unroll
    for (int o = 16; o <= 32; o <<= 1) {
        float mo  = __shfl_xor(m, o, 64);
        float lo2 = __shfl_xor(l, o, 64);
        float mn  = fmaxf(m, mo);
        float f1  = __expf(m - mn);
        float f2s = __expf(mo - mn);
        l = l * f1 + lo2 * f2s;
        f32x2 f1v = {f1, f1}, f2v = {f2s, f2s};
        #pragma unroll
        for (int j = 0; j < 4; j++) {
            f32x2 ao;
            ao.x = __shfl_xor(acc[j].x, o, 64);
            ao.y = __shfl_xor(acc[j].y, o, 64);
            acc[j] = acc[j] * f1v + ao * f2v;
        }
        m = mn;
    }

    float inv = 1.f / (l + 1e-16f);
    f32x2 hv[4];
    {
        float4 b0 = *(const float4*)(bias + fb);
        float4 b1 = *(const float4*)(bias + fb + 4);
        f32x2 iv = {inv, inv}, z = {0.f, 0.f};
        f32x2 bb0 = {b0.x, b0.y}, bb1 = {b0.z, b0.w};
        f32x2 bb2 = {b1.x, b1.y}, bb3 = {b1.z, b1.w};
        hv[0] = __builtin_elementwise_max(acc[0] * iv + bb0, z);
        hv[1] = __builtin_elementwise_max(acc[1] * iv + bb1, z);
        hv[2] = __builtin_elementwise_max(acc[2] * iv + bb2, z);
        hv[3] = __builtin_elementwise_max(acc[3] * iv + bb3, z);
    }

    if (LAST) {
        float mx = fmaxf(hv[0].x, hv[0].y);
        #pragma unroll
        for (int j = 1; j < 4; j++) mx = fmaxf(mx, fmaxf(hv[j].x, hv[j].y));
        mx = fmaxf(mx, __shfl_xor(mx, 1, 64));
        mx = fmaxf(mx, __shfl_xor(mx, 2, 64));
        mx = fmaxf(mx, __shfl_xor(mx, 4, 64));
        mx = fmaxf(mx, __shfl_xor(mx, 8, 64));
        float se = 0.f;
        #pragma unroll
        for (int j = 0; j < 4; j++) se += __expf(hv[j].x - mx) + __expf(hv[j].y - mx);
        se += __shfl_xor(se, 1, 64);
        se += __shfl_xor(se, 2, 64);
        se += __shfl_xor(se, 4, 64);
        se += __shfl_xor(se, 8, 64);
        float ls = logf(se) + mx;
        if (g == 0) {
            float4 o0 = make_float4(hv[0].x - ls, hv[0].y - ls, hv[1].x - ls, hv[1].y - ls);
            float4 o1 = make_float4(hv[2].x - ls, hv[2].y - ls, hv[3].x - ls, hv[3].y - ls);
            float* dst = outF + (size_t)i * D + fb;
            *(float4*)(dst)     = o0;
            *(float4*)(dst + 4) = o1;
        }
    } else {
        if (g < 2) {
            unsigned pk[4];
            #pragma unroll
            for (int j = 0; j < 4; j++) {
                float v0 = hv[j].x, v1 = hv[j].y;
                unsigned short h0 = f2bf_rne(v0), h1 = f2bf_rne(v1);
                if (g == 0) pk[j] = (unsigned)h0 | ((unsigned)h1 << 16);
                else {
                    unsigned short l0 = f2bf_rne(v0 - bf2f(h0));
                    unsigned short l1 = f2bf_rne(v1 - bf2f(h1));
                    pk[j] = (unsigned)l0 | ((unsigned)l1 << 16);
                }
            }
            unsigned short* dst = (g == 0 ? hhi : hlo) + (size_t)i * D + fb;
            *(uint4*)dst = make_uint4(pk[0], pk[1], pk[2], pk[3]);
        }
    }
}

extern "C" void kernel_launch(void* const* d_in, const int* in_sizes, int n_in,
                              void* d_out, int out_size, void* d_ws, size_t ws_size,
                              hipStream_t stream)
{
    const float* x    = (const float*)d_in[0];
    const int*   ei   = (const int*)  d_in[1];
    const float* Wl   = (const float*)d_in[2];
    const float* bl   = (const float*)d_in[3];
    const float* Wr   = (const float*)d_in[4];
    const float* br   = (const float*)d_in[5];
    const float* att  = (const float*)d_in[6];
    const float* bias = (const float*)d_in[7];
    float* out = (float*)d_out;

    const int* srcp = ei;
    const int* dstp = ei + N_EDGES;

    const size_t ND = (size_t)N_NODES * D;
    const size_t WSZ = (size_t)NLAYERS * D * D;
    char* ws = (char*)d_ws;
    unsigned short* xlb = (unsigned short*)ws; ws += ND * sizeof(unsigned short);
    float* xr  = (float*)ws;                   ws += ND * sizeof(float);
    unsigned short* hhi = (unsigned short*)ws; ws += ND * sizeof(unsigned short);
    unsigned short* hlo = (unsigned short*)ws; ws += ND * sizeof(unsigned short);
    unsigned short* wlh = (unsigned short*)ws; ws += WSZ * sizeof(unsigned short);
    unsigned short* wll = (unsigned short*)ws; ws += WSZ * sizeof(unsigned short);
    unsigned short* wrh = (unsigned short*)ws; ws += WSZ * sizeof(unsigned short);
    int* deg    = (int*)ws;  ws += (size_t)N_NODES * sizeof(int);
    int* incl   = (int*)ws;  ws += (size_t)N_NODES * sizeof(int);
    int* off    = (int*)ws;  ws += (size_t)(N_NODES + 1) * sizeof(int);
    int* cursor = (int*)ws;  ws += (size_t)N_NODES * sizeof(int);
    int* bsum   = (int*)ws;  ws += (size_t)NB_SCAN * sizeof(int);
    int* esrc   = (int*)ws;  ws += (size_t)ET * sizeof(int);

    const int prepGrid  = (int)((ND / 4 + 255) / 256);       // covers all three prep jobs
    const int edgeGrid  = (ET + 255) / 256;
    const int gemmGrid  = ((N_NODES + 127) / 128) * 2;       // rowBlocks x 2 col halves
    const int nodeGrid  = (N_NODES + 3) / 4;
    const int scan3Grid = (N_NODES + 1 + 255) / 256;

    // prep: split x, transpose/split weights, zero deg  (1 dispatch)
    prep_kernel<<<prepGrid, 256, 0, stream>>>(x, Wl, Wr, hhi, hlo, wlh, wll, wrh, deg);

    // CSR build (4 dispatches)
    degree_kernel<<<edgeGrid, 256, 0, stream>>>(dstp, deg);
    scan1_kernel<<<NB_SCAN, 1024, 0, stream>>>(deg, incl, bsum);
    scan3_kernel<<<scan3Grid, 256, 0, stream>>>(deg, incl, bsum, off, cursor);
    scatter_kernel<<<edgeGrid, 256, 0, stream>>>(srcp, dstp, cursor, esrc);

    for (int l = 0; l < NLAYERS; l++) {
        size_t wOff = (size_t)l * D * D;
        gemm_mfma_kernel<<<gemmGrid, 256, 0, stream>>>(
            hhi, hlo, wlh + wOff, wll + wOff, wrh + wOff,
            bl + (size_t)l * D, br + (size_t)l * D, xlb, xr, N_NODES);

        if (l == NLAYERS - 1) {
            node_attn_kernel<1><<<nodeGrid, 256, 0, stream>>>(
                xlb, xr, att + (size_t)l * D, bias + (size_t)l * D,
                off, esrc, out, nullptr, nullptr);
        } else {
            node_attn_kernel<0><<<nodeGrid, 256, 0, stream>>>(
                xlb, xr, att + (size_t)l * D, bias + (size_t)l * D,
                off, esrc, nullptr, hhi, hlo);
        }
    }
}